// Round 17
// baseline (159.025 us; speedup 1.0000x reference)
//
#include <hip/hip_runtime.h>
#include <hip/hip_bf16.h>

#define NFFT 8192
#define NH   4096
#define D    1024
#define NSEQ 4096
#define BATCH 4
#define PI_D 3.14159265358979323846

// 16-pt DFT internal constants
#define C1 0.92387953251128675613f
#define S1 0.38268343236508977173f
#define RT 0.70710678118654752440f

__device__ __forceinline__ int SWZ(int i) { return i ^ ((i >> 4) & 15) ^ ((i >> 8) & 15); }

__device__ __forceinline__ float2 cadd(float2 a, float2 b){ return make_float2(a.x+b.x, a.y+b.y); }
__device__ __forceinline__ float2 csub(float2 a, float2 b){ return make_float2(a.x-b.x, a.y-b.y); }
__device__ __forceinline__ float2 cmul(float2 a, float2 w){ return make_float2(a.x*w.x - a.y*w.y, a.x*w.y + a.y*w.x); }
__device__ __forceinline__ float2 cmulc(float2 a, float2 w){ return make_float2(a.x*w.x + a.y*w.y, a.y*w.x - a.x*w.y); }

// digit-reversal for radices [16,16,16] DIF on 4096
__device__ __forceinline__ int drev12(int k) {
    return ((k & 15) << 8) | (((k >> 4) & 15) << 4) | ((k >> 8) & 15);
}

__global__ __launch_bounds__(256) void wtab_init(float2* __restrict__ wtab) {
    int m = blockIdx.x * 256 + threadIdx.x;   // grid 16 -> 4096 entries: W8192^m
    double a = -2.0 * PI_D * (double)m / (double)NFFT;
    wtab[m] = make_float2((float)cos(a), (float)sin(a));
}

// in-register 16-pt DFT (DIF layers), in-place on v[16]
template<bool INV>
__device__ __forceinline__ void dft16(float2 v[16]) {
    float2 s[4][4];
    #pragma unroll
    for (int i = 0; i < 4; ++i) {
        float2 z0=v[i], z1=v[i+4], z2=v[i+8], z3=v[i+12];
        float2 A=cadd(z0,z2), Cc=csub(z0,z2), B=cadd(z1,z3), Dd=csub(z1,z3);
        s[i][0] = cadd(A,B);
        s[i][2] = csub(A,B);
        if (!INV) { s[i][1] = make_float2(Cc.x+Dd.y, Cc.y-Dd.x);
                    s[i][3] = make_float2(Cc.x-Dd.y, Cc.y+Dd.x); }
        else      { s[i][1] = make_float2(Cc.x-Dd.y, Cc.y+Dd.x);
                    s[i][3] = make_float2(Cc.x+Dd.y, Cc.y-Dd.x); }
    }
    if (!INV) {
        s[1][1]=cmul(s[1][1],make_float2(C1,-S1)); s[1][2]=cmul(s[1][2],make_float2(RT,-RT)); s[1][3]=cmul(s[1][3],make_float2(S1,-C1));
        s[2][1]=cmul(s[2][1],make_float2(RT,-RT)); s[2][2]=make_float2(s[2][2].y,-s[2][2].x); s[2][3]=cmul(s[2][3],make_float2(-RT,-RT));
        s[3][1]=cmul(s[3][1],make_float2(S1,-C1)); s[3][2]=cmul(s[3][2],make_float2(-RT,-RT)); s[3][3]=cmul(s[3][3],make_float2(-C1,S1));
    } else {
        s[1][1]=cmul(s[1][1],make_float2(C1,S1));  s[1][2]=cmul(s[1][2],make_float2(RT,RT));  s[1][3]=cmul(s[1][3],make_float2(S1,C1));
        s[2][1]=cmul(s[2][1],make_float2(RT,RT));  s[2][2]=make_float2(-s[2][2].y,s[2][2].x); s[2][3]=cmul(s[2][3],make_float2(-RT,RT));
        s[3][1]=cmul(s[3][1],make_float2(S1,C1));  s[3][2]=cmul(s[3][2],make_float2(-RT,RT)); s[3][3]=cmul(s[3][3],make_float2(-C1,-S1));
    }
    #pragma unroll
    for (int o = 0; o < 4; ++o) {
        float2 z0=s[0][o], z1=s[1][o], z2=s[2][o], z3=s[3][o];
        float2 A=cadd(z0,z2), Cc=csub(z0,z2), B=cadd(z1,z3), Dd=csub(z1,z3);
        v[o]    = cadd(A,B);
        v[o+8]  = csub(A,B);
        if (!INV) { v[o+4]  = make_float2(Cc.x+Dd.y, Cc.y-Dd.x);
                    v[o+12] = make_float2(Cc.x-Dd.y, Cc.y+Dd.x); }
        else      { v[o+4]  = make_float2(Cc.x-Dd.y, Cc.y+Dd.x);
                    v[o+12] = make_float2(Cc.x+Dd.y, Cc.y-Dd.x); }
    }
}

__device__ __forceinline__ void twiddle_fwd(float2 v[16], const float2* __restrict__ wt, int tw1i) {
    float2 w1 = wt[tw1i];
    float2 w2 = cmul(w1,w1), w3 = cmul(w2,w1), w4 = cmul(w2,w2), w8 = cmul(w4,w4), w12 = cmul(w8,w4);
    v[1]=cmul(v[1],w1);  v[2]=cmul(v[2],w2);  v[3]=cmul(v[3],w3);
    v[4]=cmul(v[4],w4);  v[5]=cmul(v[5],cmul(w4,w1));  v[6]=cmul(v[6],cmul(w4,w2));  v[7]=cmul(v[7],cmul(w4,w3));
    v[8]=cmul(v[8],w8);  v[9]=cmul(v[9],cmul(w8,w1));  v[10]=cmul(v[10],cmul(w8,w2)); v[11]=cmul(v[11],cmul(w8,w3));
    v[12]=cmul(v[12],w12); v[13]=cmul(v[13],cmul(w12,w1)); v[14]=cmul(v[14],cmul(w12,w2)); v[15]=cmul(v[15],cmul(w12,w3));
}
__device__ __forceinline__ void twiddle_inv(float2 v[16], const float2* __restrict__ wt, int tw1i) {
    float2 w1 = wt[tw1i];
    float2 w2 = cmul(w1,w1), w3 = cmul(w2,w1), w4 = cmul(w2,w2), w8 = cmul(w4,w4), w12 = cmul(w8,w4);
    v[1]=cmulc(v[1],w1);  v[2]=cmulc(v[2],w2);  v[3]=cmulc(v[3],w3);
    v[4]=cmulc(v[4],w4);  v[5]=cmulc(v[5],cmul(w4,w1));  v[6]=cmulc(v[6],cmul(w4,w2));  v[7]=cmulc(v[7],cmul(w4,w3));
    v[8]=cmulc(v[8],w8);  v[9]=cmulc(v[9],cmul(w8,w1));  v[10]=cmulc(v[10],cmul(w8,w2)); v[11]=cmulc(v[11],cmul(w8,w3));
    v[12]=cmulc(v[12],w12); v[13]=cmulc(v[13],cmul(w12,w1)); v[14]=cmulc(v[14],cmul(w12,w2)); v[15]=cmulc(v[15],cmul(w12,w3));
}

// 4096 middle passes (NT=256)
template<int H, bool TW, bool INV>
__device__ __forceinline__ void pass16q(float2* zs, const float2* __restrict__ wt, int t) {
    int i0, tw1i;
    if (H == 16) { int g = t >> 4, j = t & 15; i0 = g*256 + j; tw1i = 32*j; }
    else         { i0 = t*16; tw1i = 0; }
    float2 v[16];
    #pragma unroll
    for (int q = 0; q < 16; ++q) v[q] = zs[SWZ(i0 + H*q)];
    if (INV && TW) twiddle_inv(v, wt, tw1i);
    dft16<INV>(v);
    if (!INV && TW) twiddle_fwd(v, wt, tw1i);
    #pragma unroll
    for (int r = 0; r < 16; ++r) zs[SWZ(i0 + H*r)] = v[r];
}

// ---------- tspec (real-4096 even/odd), PACKED input tQ[c][n] ----------
// z[n] = t[2n] + i*t[2n+1]; FFT-4096; T[k] = E + W8192^k*O, T[4096-k] = conj(E - W8192^k*O).
// tsPall[c][it*256+t] = (T[k], T[4096-k]) in conv's exact read enumeration; slot 2048 = k=2048.
template<int PACKED>
__global__ __launch_bounds__(256, 2) void tspec_kernel(const float* __restrict__ tQ,
                                                       const float* __restrict__ tg,
                                                       const float2* __restrict__ wt,
                                                       float4* __restrict__ tsPall) {
    __shared__ float2 zs[4096];
    int wg = blockIdx.x;
    int c  = (wg & 7) * 128 + (wg >> 3);    // XCD swizzle: 128 contiguous c per XCD
    int t  = threadIdx.x;

    {
        float2 v[16];
        if (PACKED) {
            const float* slab = tQ + (size_t)c * NFFT;
            #pragma unroll
            for (int q = 0; q < 16; ++q) v[q] = *(const float2*)(slab + 2*(t + 256*q));
        } else {
            const float* tb = tg + c;
            #pragma unroll
            for (int q = 0; q < 16; ++q) {
                int n = t + 256*q;
                v[q] = make_float2(tb[(size_t)(2*n) * D], tb[(size_t)(2*n+1) * D]);
            }
        }
        dft16<false>(v);
        twiddle_fwd(v, wt, 2*t);
        #pragma unroll
        for (int r = 0; r < 16; ++r) zs[SWZ(t + 256*r)] = v[r];
    }
    __syncthreads();
    pass16q<16, true,  false>(zs, wt, t); __syncthreads();
    pass16q<1,  false, false>(zs, wt, t); __syncthreads();

    float4* o = tsPall + (size_t)c * 2049;
    #pragma unroll
    for (int it = 0; it < 8; ++it) {
        int k  = ((t & 7) << 8) | ((t >> 3) << 3) | it;
        int p1 = drev12(k);
        int p2 = drev12((4096 - k) & 4095);
        float2 Zk = zs[SWZ(p1)], Zp = zs[SWZ(p2)];
        float Er = 0.5f*(Zk.x + Zp.x), Ei = 0.5f*(Zk.y - Zp.y);
        float Or = 0.5f*(Zk.y + Zp.y), Oi = 0.5f*(Zp.x - Zk.x);
        float2 w = wt[k];
        float WOr = Or*w.x - Oi*w.y, WOi = Or*w.y + Oi*w.x;
        // T[k] = E + WO ; T[4096-k] = conj(E - WO)
        o[it * 256 + t] = make_float4(Er + WOr, Ei + WOi, Er - WOr, WOi - Ei);
    }
    if (t == 0) {   // k = 2048: E=(Z.x,0), O=(Z.y,0), w=-i -> T = (Z.x, -Z.y); pair = itself
        float2 Zk = zs[SWZ(drev12(2048))];
        o[2048] = make_float4(Zk.x, -Zk.y, Zk.x, -Zk.y);
    }
}

// One real-conv spectral pair (k, 4096-k): X=A+W·B / conj(A-W·B); Y=X·T; W=E+iO repack.
// Generic for ALL k in [0,2048] (k=0 and k=2048 double-write identical values — verified).
__device__ __forceinline__ void conv_pair(float2* zs, const float2* __restrict__ wt,
                                          float4 Tq, int k) {
    int p1 = drev12(k);
    int kp = (4096 - k) & 4095;
    int p2 = drev12(kp);
    float2 Zk = zs[SWZ(p1)], Zp = zs[SWZ(p2)];
    float2 w = wt[k];                                     // W8192^k
    float Ar = 0.5f*(Zk.x + Zp.x), Ai = 0.5f*(Zk.y - Zp.y);
    float Br = 0.5f*(Zk.y + Zp.y), Bi = 0.5f*(Zp.x - Zk.x);
    float2 WB = make_float2(w.x*Br - w.y*Bi, w.x*Bi + w.y*Br);
    float2 X1 = make_float2(Ar + WB.x, Ai + WB.y);        // X[k]
    float2 X2 = make_float2(Ar - WB.x, WB.y - Ai);        // X[4096-k] = conj(A - W·B)
    float2 Y1 = make_float2(X1.x*Tq.x - X1.y*Tq.y, X1.x*Tq.y + X1.y*Tq.x);
    float2 Y2 = make_float2(X2.x*Tq.z - X2.y*Tq.w, X2.x*Tq.w + X2.y*Tq.z);
    float Er = 0.5f*(Y1.x + Y2.x), Ei = 0.5f*(Y1.y - Y2.y);
    float Gr = 0.5f*(Y1.x - Y2.x), Gi = 0.5f*(Y1.y + Y2.y);
    float O1x = Gr*w.x + Gi*w.y, O1y = Gi*w.x - Gr*w.y;   // O1 = G*conj(w)
    float O2x = O1x,             O2y = Gr*w.y - Gi*w.x;   // O2 = conj(G)*w
    zs[SWZ(p1)] = make_float2(Er - O1y, Ei + O1x);        // W[k]      = E + i*O1
    zs[SWZ(p2)] = make_float2(Er - O2y, O2x - Ei);        // W[4096-k] = conj(E) + i*O2
}

// ---------- conv (round-14/16 proven): packed read, packed in-place write ----------
template<int PACKED>
__global__ __launch_bounds__(256, 2) void conv_kernel(float* __restrict__ region,
                                                      const float* __restrict__ xg,
                                                      float* __restrict__ outg,
                                                      const float2* __restrict__ wt,
                                                      const float4* __restrict__ tsPall) {
    __shared__ float2 zs[4096];
    int wg  = blockIdx.x;
    int c   = (wg & 7) * 128 + ((wg >> 3) & 127);   // XCD swizzle: 128 contiguous c per XCD
    int b   = wg >> 10;
    int t   = threadIdx.x;

    float* slab = PACKED ? (region + ((size_t)c * BATCH + b) * NSEQ) : nullptr;

    // ---- fwd stage1 (H=256) fused with load: z[n] = x[2n] + i*x[2n+1], zero-padded
    {
        float2 v[16];
        if (PACKED) {
            #pragma unroll
            for (int q = 0; q < 8; ++q) v[q] = *(const float2*)(slab + 2*(t + 256*q));
        } else {
            const float* xb = xg + (size_t)b * NSEQ * D + c;
            #pragma unroll
            for (int q = 0; q < 8; ++q) {
                int n = t + 256*q;
                v[q] = make_float2(xb[(size_t)(2*n) * D], xb[(size_t)(2*n+1) * D]);
            }
        }
        #pragma unroll
        for (int q = 8; q < 16; ++q) v[q] = make_float2(0.f, 0.f);
        dft16<false>(v);
        twiddle_fwd(v, wt, 2*t);
        #pragma unroll
        for (int r = 0; r < 16; ++r) zs[SWZ(t + 256*r)] = v[r];
    }
    __syncthreads();
    pass16q<16, true,  false>(zs, wt, t); __syncthreads();
    pass16q<1,  false, false>(zs, wt, t); __syncthreads();

    // ---- untangle * T * repack (T slot-ordered coalesced; pairs race-free)
    const float4* tsP = tsPall + (size_t)c * 2049;
    #pragma unroll
    for (int it = 0; it < 8; ++it) {
        int k = ((t & 7) << 8) | ((t >> 3) << 3) | it;
        conv_pair(zs, wt, tsP[it * 256 + t], k);
    }
    if (t == 0) conv_pair(zs, wt, tsP[2048], 2048);
    __syncthreads();

    pass16q<1,  false, true>(zs, wt, t); __syncthreads();
    pass16q<16, true,  true>(zs, wt, t); __syncthreads();

    // ---- inv stage (H=256) fused with store: w[n]=(y[2n],y[2n+1]); n<2048 only
    {
        float2 v[16];
        #pragma unroll
        for (int q = 0; q < 16; ++q) v[q] = zs[SWZ(t + 256*q)];
        twiddle_inv(v, wt, 2*t);
        dft16<true>(v);
        const float sc = 1.0f / 4096.0f;
        if (PACKED) {
            #pragma unroll
            for (int r = 0; r < 8; ++r) {
                int n = t + 256*r;
                *(float2*)(slab + 2*n) = make_float2(v[r].x * sc, v[r].y * sc);
            }
        } else {
            float* ob = outg + (size_t)b * NSEQ * D + c;
            #pragma unroll
            for (int r = 0; r < 8; ++r) {
                int n = t + 256*r;
                ob[(size_t)(2*n) * D]   = v[r].x * sc;
                ob[(size_t)(2*n+1) * D] = v[r].y * sc;
            }
        }
    }
}

// ---------- pack: in(b,n,d) -> q[c][b][n], float4 on BOTH global sides ----------
// LDS tile [64][65]: stride-4 scalar writes = 2-way bank (free, m136); column reads
// stride-65 = conflict-free. Global float4 addrs 16B-aligned (n0,d0 mult 64; D,NSEQ mult 4).
__global__ __launch_bounds__(256) void pack_Q(const float* __restrict__ in,
                                              float* __restrict__ q,
                                              int Nrows, int Bsz) {
    __shared__ float tile[64][65];
    int tid = threadIdx.x;
    int n0 = blockIdx.x * 64, d0 = blockIdx.y * 64, b = blockIdx.z;
    const float* ib = in + (size_t)b * Nrows * D;
    int dq = tid & 15, nr = tid >> 4;
    #pragma unroll
    for (int it = 0; it < 4; ++it) {
        int n_l = nr + 16 * it;
        float4 v = *(const float4*)(ib + (size_t)(n0 + n_l) * D + d0 + 4 * dq);
        tile[n_l][4*dq+0] = v.x; tile[n_l][4*dq+1] = v.y;
        tile[n_l][4*dq+2] = v.z; tile[n_l][4*dq+3] = v.w;
    }
    __syncthreads();
    int nq = tid & 15, cr = tid >> 4;
    #pragma unroll
    for (int it = 0; it < 4; ++it) {
        int c_l = cr + 16 * it;
        float4 v = make_float4(tile[4*nq+0][c_l], tile[4*nq+1][c_l],
                               tile[4*nq+2][c_l], tile[4*nq+3][c_l]);
        *(float4*)(q + ((size_t)(d0 + c_l) * Bsz + b) * Nrows + n0 + 4 * nq) = v;
    }
}

// ---------- unpack: oQ[c][b][n] -> out(b,n,d), float4 on BOTH global sides ----------
__global__ __launch_bounds__(256) void unpack_Q(const float* __restrict__ q,
                                                float* __restrict__ outp) {
    __shared__ float tile[64][65];
    int tid = threadIdx.x;
    int n0 = blockIdx.x * 64, d0 = blockIdx.y * 64, b = blockIdx.z;
    int nq = tid & 15, cr = tid >> 4;
    #pragma unroll
    for (int it = 0; it < 4; ++it) {
        int c_l = cr + 16 * it;
        float4 v = *(const float4*)(q + ((size_t)(d0 + c_l) * BATCH + b) * NSEQ + n0 + 4 * nq);
        tile[4*nq+0][c_l] = v.x; tile[4*nq+1][c_l] = v.y;
        tile[4*nq+2][c_l] = v.z; tile[4*nq+3][c_l] = v.w;
    }
    __syncthreads();
    float* ob = outp + (size_t)b * NSEQ * D;
    int dq = tid & 15, nr = tid >> 4;
    #pragma unroll
    for (int it = 0; it < 4; ++it) {
        int n_l = nr + 16 * it;
        float4 v = make_float4(tile[n_l][4*dq+0], tile[n_l][4*dq+1],
                               tile[n_l][4*dq+2], tile[n_l][4*dq+3]);
        *(float4*)(ob + (size_t)(n0 + n_l) * D + d0 + 4 * dq) = v;
    }
}

extern "C" void kernel_launch(void* const* d_in, const int* in_sizes, int n_in,
                              void* d_out, int out_size, void* d_ws, size_t ws_size,
                              hipStream_t stream) {
    const float* x = (const float*)d_in[0];   // (4, 4096, 1024) f32
    const float* t = (const float*)d_in[1];   // (8192, 1024) f32
    float* outp = (float*)d_out;              // (4, 4096, 1024) f32

    char* ws = (char*)d_ws;
    float2* wtab   = (float2*)ws;                                   // 32 KB used, 64 KB reserved
    float4* tsPall = (float4*)(ws + 65536);                         // 1024*2049*16 = 33,570,816
    const size_t OFF_Q = 65536 + (size_t)1024 * 2049 * 16;
    float* region = (float*)(ws + OFF_Q);                           // tQ (32MB) then xQ/oQ (64MB)
    const size_t need_full = OFF_Q + (size_t)1024 * BATCH * NSEQ * sizeof(float); // ~96.1 MB

    wtab_init<<<16, 256, 0, stream>>>(wtab);

    if (ws_size >= need_full) {
        // pack t -> region (tQ[c][0..8191]); tspec consumes it; then region reused for xQ
        pack_Q<<<dim3(128, 16, 1), 256, 0, stream>>>(t, region, NFFT, 1);
        tspec_kernel<1><<<1024, 256, 0, stream>>>(region, nullptr, wtab, tsPall);
        pack_Q<<<dim3(64, 16, BATCH), 256, 0, stream>>>(x, region, NSEQ, BATCH);
        conv_kernel<1><<<1024 * BATCH, 256, 0, stream>>>(region, nullptr, nullptr, wtab, tsPall);
        unpack_Q<<<dim3(64, 16, BATCH), 256, 0, stream>>>(region, outp);
    } else {
        // fallback (ws >= ~33.6MB proven): strided reads/writes, slower but correct
        tspec_kernel<0><<<1024, 256, 0, stream>>>(nullptr, t, wtab, tsPall);
        conv_kernel<0><<<1024 * BATCH, 256, 0, stream>>>(nullptr, x, outp, wtab, tsPall);
    }
}

// Round 18
// 152.257 us; speedup vs baseline: 1.0445x; 1.0445x over previous
//
#include <hip/hip_runtime.h>
#include <hip/hip_bf16.h>

#define NFFT 8192
#define NH   4096
#define D    1024
#define NSEQ 4096
#define BATCH 4
#define PI_D 3.14159265358979323846

// 16-pt DFT internal constants
#define C1 0.92387953251128675613f
#define S1 0.38268343236508977173f
#define RT 0.70710678118654752440f

__device__ __forceinline__ int SWZ(int i) { return i ^ ((i >> 4) & 15) ^ ((i >> 8) & 15); }

__device__ __forceinline__ float2 cadd(float2 a, float2 b){ return make_float2(a.x+b.x, a.y+b.y); }
__device__ __forceinline__ float2 csub(float2 a, float2 b){ return make_float2(a.x-b.x, a.y-b.y); }
__device__ __forceinline__ float2 cmul(float2 a, float2 w){ return make_float2(a.x*w.x - a.y*w.y, a.x*w.y + a.y*w.x); }
__device__ __forceinline__ float2 cmulc(float2 a, float2 w){ return make_float2(a.x*w.x + a.y*w.y, a.y*w.x - a.x*w.y); }

// digit-reversal for radices [16,16,16] DIF on 4096
__device__ __forceinline__ int drev12(int k) {
    return ((k & 15) << 8) | (((k >> 4) & 15) << 4) | ((k >> 8) & 15);
}

__global__ __launch_bounds__(256) void wtab_init(float2* __restrict__ wtab) {
    int m = blockIdx.x * 256 + threadIdx.x;   // grid 16 -> 4096 entries: W8192^m
    double a = -2.0 * PI_D * (double)m / (double)NFFT;
    wtab[m] = make_float2((float)cos(a), (float)sin(a));
}

// in-register 16-pt DFT (DIF layers), in-place on v[16]
template<bool INV>
__device__ __forceinline__ void dft16(float2 v[16]) {
    float2 s[4][4];
    #pragma unroll
    for (int i = 0; i < 4; ++i) {
        float2 z0=v[i], z1=v[i+4], z2=v[i+8], z3=v[i+12];
        float2 A=cadd(z0,z2), Cc=csub(z0,z2), B=cadd(z1,z3), Dd=csub(z1,z3);
        s[i][0] = cadd(A,B);
        s[i][2] = csub(A,B);
        if (!INV) { s[i][1] = make_float2(Cc.x+Dd.y, Cc.y-Dd.x);
                    s[i][3] = make_float2(Cc.x-Dd.y, Cc.y+Dd.x); }
        else      { s[i][1] = make_float2(Cc.x-Dd.y, Cc.y+Dd.x);
                    s[i][3] = make_float2(Cc.x+Dd.y, Cc.y-Dd.x); }
    }
    if (!INV) {
        s[1][1]=cmul(s[1][1],make_float2(C1,-S1)); s[1][2]=cmul(s[1][2],make_float2(RT,-RT)); s[1][3]=cmul(s[1][3],make_float2(S1,-C1));
        s[2][1]=cmul(s[2][1],make_float2(RT,-RT)); s[2][2]=make_float2(s[2][2].y,-s[2][2].x); s[2][3]=cmul(s[2][3],make_float2(-RT,-RT));
        s[3][1]=cmul(s[3][1],make_float2(S1,-C1)); s[3][2]=cmul(s[3][2],make_float2(-RT,-RT)); s[3][3]=cmul(s[3][3],make_float2(-C1,S1));
    } else {
        s[1][1]=cmul(s[1][1],make_float2(C1,S1));  s[1][2]=cmul(s[1][2],make_float2(RT,RT));  s[1][3]=cmul(s[1][3],make_float2(S1,C1));
        s[2][1]=cmul(s[2][1],make_float2(RT,RT));  s[2][2]=make_float2(-s[2][2].y,s[2][2].x); s[2][3]=cmul(s[2][3],make_float2(-RT,RT));
        s[3][1]=cmul(s[3][1],make_float2(S1,C1));  s[3][2]=cmul(s[3][2],make_float2(-RT,RT)); s[3][3]=cmul(s[3][3],make_float2(-C1,-S1));
    }
    #pragma unroll
    for (int o = 0; o < 4; ++o) {
        float2 z0=s[0][o], z1=s[1][o], z2=s[2][o], z3=s[3][o];
        float2 A=cadd(z0,z2), Cc=csub(z0,z2), B=cadd(z1,z3), Dd=csub(z1,z3);
        v[o]    = cadd(A,B);
        v[o+8]  = csub(A,B);
        if (!INV) { v[o+4]  = make_float2(Cc.x+Dd.y, Cc.y-Dd.x);
                    v[o+12] = make_float2(Cc.x-Dd.y, Cc.y+Dd.x); }
        else      { v[o+4]  = make_float2(Cc.x-Dd.y, Cc.y+Dd.x);
                    v[o+12] = make_float2(Cc.x+Dd.y, Cc.y-Dd.x); }
    }
}

__device__ __forceinline__ void twiddle_fwd(float2 v[16], const float2* __restrict__ wt, int tw1i) {
    float2 w1 = wt[tw1i];
    float2 w2 = cmul(w1,w1), w3 = cmul(w2,w1), w4 = cmul(w2,w2), w8 = cmul(w4,w4), w12 = cmul(w8,w4);
    v[1]=cmul(v[1],w1);  v[2]=cmul(v[2],w2);  v[3]=cmul(v[3],w3);
    v[4]=cmul(v[4],w4);  v[5]=cmul(v[5],cmul(w4,w1));  v[6]=cmul(v[6],cmul(w4,w2));  v[7]=cmul(v[7],cmul(w4,w3));
    v[8]=cmul(v[8],w8);  v[9]=cmul(v[9],cmul(w8,w1));  v[10]=cmul(v[10],cmul(w8,w2)); v[11]=cmul(v[11],cmul(w8,w3));
    v[12]=cmul(v[12],w12); v[13]=cmul(v[13],cmul(w12,w1)); v[14]=cmul(v[14],cmul(w12,w2)); v[15]=cmul(v[15],cmul(w12,w3));
}
__device__ __forceinline__ void twiddle_inv(float2 v[16], const float2* __restrict__ wt, int tw1i) {
    float2 w1 = wt[tw1i];
    float2 w2 = cmul(w1,w1), w3 = cmul(w2,w1), w4 = cmul(w2,w2), w8 = cmul(w4,w4), w12 = cmul(w8,w4);
    v[1]=cmulc(v[1],w1);  v[2]=cmulc(v[2],w2);  v[3]=cmulc(v[3],w3);
    v[4]=cmulc(v[4],w4);  v[5]=cmulc(v[5],cmul(w4,w1));  v[6]=cmulc(v[6],cmul(w4,w2));  v[7]=cmulc(v[7],cmul(w4,w3));
    v[8]=cmulc(v[8],w8);  v[9]=cmulc(v[9],cmul(w8,w1));  v[10]=cmulc(v[10],cmul(w8,w2)); v[11]=cmulc(v[11],cmul(w8,w3));
    v[12]=cmulc(v[12],w12); v[13]=cmulc(v[13],cmul(w12,w1)); v[14]=cmulc(v[14],cmul(w12,w2)); v[15]=cmulc(v[15],cmul(w12,w3));
}

// 4096 middle passes (NT=256)
template<int H, bool TW, bool INV>
__device__ __forceinline__ void pass16q(float2* zs, const float2* __restrict__ wt, int t) {
    int i0, tw1i;
    if (H == 16) { int g = t >> 4, j = t & 15; i0 = g*256 + j; tw1i = 32*j; }
    else         { i0 = t*16; tw1i = 0; }
    float2 v[16];
    #pragma unroll
    for (int q = 0; q < 16; ++q) v[q] = zs[SWZ(i0 + H*q)];
    if (INV && TW) twiddle_inv(v, wt, tw1i);
    dft16<INV>(v);
    if (!INV && TW) twiddle_fwd(v, wt, tw1i);
    #pragma unroll
    for (int r = 0; r < 16; ++r) zs[SWZ(i0 + H*r)] = v[r];
}

// ---------- tspec (real-4096 even/odd), PACKED input tQ[c][n] ----------
// z[n] = t[2n] + i*t[2n+1]; FFT-4096; T[k] = E + W8192^k*O, T[4096-k] = conj(E - W8192^k*O).
// tsPall[c][it*256+t] = (T[k], T[4096-k]) in conv's exact read enumeration; slot 2048 = k=2048.
template<int PACKED>
__global__ __launch_bounds__(256, 2) void tspec_kernel(const float* __restrict__ tQ,
                                                       const float* __restrict__ tg,
                                                       const float2* __restrict__ wt,
                                                       float4* __restrict__ tsPall) {
    __shared__ float2 zs[4096];
    int wg = blockIdx.x;
    int c  = (wg & 7) * 128 + (wg >> 3);    // XCD swizzle: 128 contiguous c per XCD
    int t  = threadIdx.x;

    {
        float2 v[16];
        if (PACKED) {
            const float* slab = tQ + (size_t)c * NFFT;
            #pragma unroll
            for (int q = 0; q < 16; ++q) v[q] = *(const float2*)(slab + 2*(t + 256*q));
        } else {
            const float* tb = tg + c;
            #pragma unroll
            for (int q = 0; q < 16; ++q) {
                int n = t + 256*q;
                v[q] = make_float2(tb[(size_t)(2*n) * D], tb[(size_t)(2*n+1) * D]);
            }
        }
        dft16<false>(v);
        twiddle_fwd(v, wt, 2*t);
        #pragma unroll
        for (int r = 0; r < 16; ++r) zs[SWZ(t + 256*r)] = v[r];
    }
    __syncthreads();
    pass16q<16, true,  false>(zs, wt, t); __syncthreads();
    pass16q<1,  false, false>(zs, wt, t); __syncthreads();

    float4* o = tsPall + (size_t)c * 2049;
    #pragma unroll
    for (int it = 0; it < 8; ++it) {
        int k  = ((t & 7) << 8) | ((t >> 3) << 3) | it;
        int p1 = drev12(k);
        int p2 = drev12((4096 - k) & 4095);
        float2 Zk = zs[SWZ(p1)], Zp = zs[SWZ(p2)];
        float Er = 0.5f*(Zk.x + Zp.x), Ei = 0.5f*(Zk.y - Zp.y);
        float Or = 0.5f*(Zk.y + Zp.y), Oi = 0.5f*(Zp.x - Zk.x);
        float2 w = wt[k];
        float WOr = Or*w.x - Oi*w.y, WOi = Or*w.y + Oi*w.x;
        // T[k] = E + WO ; T[4096-k] = conj(E - WO)
        o[it * 256 + t] = make_float4(Er + WOr, Ei + WOi, Er - WOr, WOi - Ei);
    }
    if (t == 0) {   // k = 2048: E=(Z.x,0), O=(Z.y,0), w=-i -> T = (Z.x, -Z.y); pair = itself
        float2 Zk = zs[SWZ(drev12(2048))];
        o[2048] = make_float4(Zk.x, -Zk.y, Zk.x, -Zk.y);
    }
}

// One real-conv spectral pair (k, 4096-k): X=A+W·B / conj(A-W·B); Y=X·T; W=E+iO repack.
// Generic for ALL k in [0,2048] (k=0 and k=2048 double-write identical values — verified).
__device__ __forceinline__ void conv_pair(float2* zs, const float2* __restrict__ wt,
                                          float4 Tq, int k) {
    int p1 = drev12(k);
    int kp = (4096 - k) & 4095;
    int p2 = drev12(kp);
    float2 Zk = zs[SWZ(p1)], Zp = zs[SWZ(p2)];
    float2 w = wt[k];                                     // W8192^k
    float Ar = 0.5f*(Zk.x + Zp.x), Ai = 0.5f*(Zk.y - Zp.y);
    float Br = 0.5f*(Zk.y + Zp.y), Bi = 0.5f*(Zp.x - Zk.x);
    float2 WB = make_float2(w.x*Br - w.y*Bi, w.x*Bi + w.y*Br);
    float2 X1 = make_float2(Ar + WB.x, Ai + WB.y);        // X[k]
    float2 X2 = make_float2(Ar - WB.x, WB.y - Ai);        // X[4096-k] = conj(A - W·B)
    float2 Y1 = make_float2(X1.x*Tq.x - X1.y*Tq.y, X1.x*Tq.y + X1.y*Tq.x);
    float2 Y2 = make_float2(X2.x*Tq.z - X2.y*Tq.w, X2.x*Tq.w + X2.y*Tq.z);
    float Er = 0.5f*(Y1.x + Y2.x), Ei = 0.5f*(Y1.y - Y2.y);
    float Gr = 0.5f*(Y1.x - Y2.x), Gi = 0.5f*(Y1.y + Y2.y);
    float O1x = Gr*w.x + Gi*w.y, O1y = Gi*w.x - Gr*w.y;   // O1 = G*conj(w)
    float O2x = O1x,             O2y = Gr*w.y - Gi*w.x;   // O2 = conj(G)*w
    zs[SWZ(p1)] = make_float2(Er - O1y, Ei + O1x);        // W[k]      = E + i*O1
    zs[SWZ(p2)] = make_float2(Er - O2y, O2x - Ei);        // W[4096-k] = conj(E) + i*O2
}

// ---------- conv (round-14/16 proven): packed read, packed in-place write ----------
template<int PACKED>
__global__ __launch_bounds__(256, 2) void conv_kernel(float* __restrict__ region,
                                                      const float* __restrict__ xg,
                                                      float* __restrict__ outg,
                                                      const float2* __restrict__ wt,
                                                      const float4* __restrict__ tsPall) {
    __shared__ float2 zs[4096];
    int wg  = blockIdx.x;
    int c   = (wg & 7) * 128 + ((wg >> 3) & 127);   // XCD swizzle: 128 contiguous c per XCD
    int b   = wg >> 10;
    int t   = threadIdx.x;

    float* slab = PACKED ? (region + ((size_t)c * BATCH + b) * NSEQ) : nullptr;

    // ---- fwd stage1 (H=256) fused with load: z[n] = x[2n] + i*x[2n+1], zero-padded
    {
        float2 v[16];
        if (PACKED) {
            #pragma unroll
            for (int q = 0; q < 8; ++q) v[q] = *(const float2*)(slab + 2*(t + 256*q));
        } else {
            const float* xb = xg + (size_t)b * NSEQ * D + c;
            #pragma unroll
            for (int q = 0; q < 8; ++q) {
                int n = t + 256*q;
                v[q] = make_float2(xb[(size_t)(2*n) * D], xb[(size_t)(2*n+1) * D]);
            }
        }
        #pragma unroll
        for (int q = 8; q < 16; ++q) v[q] = make_float2(0.f, 0.f);
        dft16<false>(v);
        twiddle_fwd(v, wt, 2*t);
        #pragma unroll
        for (int r = 0; r < 16; ++r) zs[SWZ(t + 256*r)] = v[r];
    }
    __syncthreads();
    pass16q<16, true,  false>(zs, wt, t); __syncthreads();
    pass16q<1,  false, false>(zs, wt, t); __syncthreads();

    // ---- untangle * T * repack (T slot-ordered coalesced; pairs race-free)
    const float4* tsP = tsPall + (size_t)c * 2049;
    #pragma unroll
    for (int it = 0; it < 8; ++it) {
        int k = ((t & 7) << 8) | ((t >> 3) << 3) | it;
        conv_pair(zs, wt, tsP[it * 256 + t], k);
    }
    if (t == 0) conv_pair(zs, wt, tsP[2048], 2048);
    __syncthreads();

    pass16q<1,  false, true>(zs, wt, t); __syncthreads();
    pass16q<16, true,  true>(zs, wt, t); __syncthreads();

    // ---- inv stage (H=256) fused with store: w[n]=(y[2n],y[2n+1]); n<2048 only
    {
        float2 v[16];
        #pragma unroll
        for (int q = 0; q < 16; ++q) v[q] = zs[SWZ(t + 256*q)];
        twiddle_inv(v, wt, 2*t);
        dft16<true>(v);
        const float sc = 1.0f / 4096.0f;
        if (PACKED) {
            #pragma unroll
            for (int r = 0; r < 8; ++r) {
                int n = t + 256*r;
                *(float2*)(slab + 2*n) = make_float2(v[r].x * sc, v[r].y * sc);
            }
        } else {
            float* ob = outg + (size_t)b * NSEQ * D + c;
            #pragma unroll
            for (int r = 0; r < 8; ++r) {
                int n = t + 256*r;
                ob[(size_t)(2*n) * D]   = v[r].x * sc;
                ob[(size_t)(2*n+1) * D] = v[r].y * sc;
            }
        }
    }
}

// ---------- pack: in(b,n,d) -> q[c][b][n] (generic tile transpose; R16 proven form) ----------
__global__ __launch_bounds__(256) void pack_Q(const float* __restrict__ in,
                                              float* __restrict__ q,
                                              int Nrows, int Bsz) {
    __shared__ float tile[64][65];
    int tid = threadIdx.x;
    int n0 = blockIdx.x * 64, d0 = blockIdx.y * 64, b = blockIdx.z;
    const float* ib = in + (size_t)b * Nrows * D;
    #pragma unroll
    for (int it = 0; it < 16; ++it) {
        int n_l = it * 4 + (tid >> 6);
        int d_l = tid & 63;
        tile[n_l][d_l] = ib[(size_t)(n0 + n_l) * D + d0 + d_l];
    }
    __syncthreads();
    #pragma unroll
    for (int it = 0; it < 16; ++it) {
        int flat = it * 256 + tid;
        int c_l = flat >> 6;
        int n_l = flat & 63;
        q[((size_t)(d0 + c_l) * Bsz + b) * Nrows + n0 + n_l] = tile[n_l][c_l];
    }
}

// ---------- unpack: oQ[c][b][n] -> out(b,n,d) (R16 proven form) ----------
__global__ __launch_bounds__(256) void unpack_Q(const float* __restrict__ q,
                                                float* __restrict__ outp) {
    __shared__ float tile[64][65];
    int tid = threadIdx.x;
    int n0 = blockIdx.x * 64, d0 = blockIdx.y * 64, b = blockIdx.z;
    #pragma unroll
    for (int it = 0; it < 16; ++it) {
        int flat = it * 256 + tid;
        int c_l = flat >> 6;
        int n_l = flat & 63;
        tile[c_l][n_l] = q[((size_t)(d0 + c_l) * BATCH + b) * NSEQ + n0 + n_l];
    }
    __syncthreads();
    float* ob = outp + (size_t)b * NSEQ * D;
    #pragma unroll
    for (int it = 0; it < 16; ++it) {
        int n_l = it * 4 + (tid >> 6);
        int d_l = tid & 63;
        ob[(size_t)(n0 + n_l) * D + d0 + d_l] = tile[d_l][n_l];
    }
}

extern "C" void kernel_launch(void* const* d_in, const int* in_sizes, int n_in,
                              void* d_out, int out_size, void* d_ws, size_t ws_size,
                              hipStream_t stream) {
    const float* x = (const float*)d_in[0];   // (4, 4096, 1024) f32
    const float* t = (const float*)d_in[1];   // (8192, 1024) f32
    float* outp = (float*)d_out;              // (4, 4096, 1024) f32

    char* ws = (char*)d_ws;
    float2* wtab   = (float2*)ws;                                   // 32 KB used, 64 KB reserved
    float4* tsPall = (float4*)(ws + 65536);                         // 1024*2049*16 = 33,570,816
    const size_t OFF_Q = 65536 + (size_t)1024 * 2049 * 16;
    float* region = (float*)(ws + OFF_Q);                           // tQ (32MB) then xQ/oQ (64MB)
    const size_t need_full = OFF_Q + (size_t)1024 * BATCH * NSEQ * sizeof(float); // ~96.1 MB

    wtab_init<<<16, 256, 0, stream>>>(wtab);

    if (ws_size >= need_full) {
        // pack t -> region (tQ[c][0..8191]); tspec consumes it; then region reused for xQ
        pack_Q<<<dim3(128, 16, 1), 256, 0, stream>>>(t, region, NFFT, 1);
        tspec_kernel<1><<<1024, 256, 0, stream>>>(region, nullptr, wtab, tsPall);
        pack_Q<<<dim3(64, 16, BATCH), 256, 0, stream>>>(x, region, NSEQ, BATCH);
        conv_kernel<1><<<1024 * BATCH, 256, 0, stream>>>(region, nullptr, nullptr, wtab, tsPall);
        unpack_Q<<<dim3(64, 16, BATCH), 256, 0, stream>>>(region, outp);
    } else {
        // fallback (ws >= ~33.6MB proven): strided reads/writes, slower but correct
        tspec_kernel<0><<<1024, 256, 0, stream>>>(nullptr, t, wtab, tsPall);
        conv_kernel<0><<<1024 * BATCH, 256, 0, stream>>>(nullptr, x, outp, wtab, tsPall);
    }
}